// Round 4
// baseline (207.420 us; speedup 1.0000x reference)
//
#include <hip/hip_runtime.h>

typedef float f4 __attribute__((ext_vector_type(4)));
typedef float f32x4 __attribute__((ext_vector_type(4)));
typedef short bf16x8 __attribute__((ext_vector_type(8)));
typedef unsigned short u16x8 __attribute__((ext_vector_type(8)));

static __device__ __forceinline__ unsigned short f2bf(float f) {
    unsigned int x = __builtin_bit_cast(unsigned int, f);
    x = (x + 0x7fffu + ((x >> 16) & 1u)) >> 16;
    return (unsigned short)x;
}
static __device__ __forceinline__ float bf2f(unsigned short h) {
    unsigned int x = ((unsigned int)h) << 16;
    return __builtin_bit_cast(float, x);
}

// ---------------- convert: f32 -> (bf16 hi, bf16 lo) planes, 5 tensors fused
struct CvtJob { const float* src; unsigned short* hi; unsigned short* lo; int n8; };

__global__ __launch_bounds__(256) void convert_kernel(
    CvtJob j0, CvtJob j1, CvtJob j2, CvtJob j3, CvtJob j4, int total8)
{
    CvtJob jobs[5] = { j0, j1, j2, j3, j4 };
    int cum1 = j0.n8, cum2 = cum1 + j1.n8, cum3 = cum2 + j2.n8, cum4 = cum3 + j3.n8;
    for (int g = blockIdx.x * blockDim.x + threadIdx.x; g < total8;
         g += gridDim.x * blockDim.x) {
        int ji, base;
        if      (g < cum1) { ji = 0; base = 0; }
        else if (g < cum2) { ji = 1; base = cum1; }
        else if (g < cum3) { ji = 2; base = cum2; }
        else if (g < cum4) { ji = 3; base = cum3; }
        else               { ji = 4; base = cum4; }
        const CvtJob& J = jobs[ji];
        int idx = (g - base) * 8;
        f4 a = *(const f4*)(J.src + idx);
        f4 b = *(const f4*)(J.src + idx + 4);
        u16x8 hv, lv;
        float s[8] = { a.x, a.y, a.z, a.w, b.x, b.y, b.z, b.w };
        #pragma unroll
        for (int i = 0; i < 8; ++i) {
            unsigned short h = f2bf(s[i]);
            hv[i] = h;
            lv[i] = f2bf(s[i] - bf2f(h));
        }
        *(u16x8*)(J.hi + idx) = hv;
        *(u16x8*)(J.lo + idx) = lv;
    }
}

// ---------------- merged split-bf16 MFMA GEMM, 64x64 tiles, 2 jobs per launch
struct GJob {
    const unsigned short *Ah, *Al, *Wh, *Wl;
    int lda, ldw;
    const float* bias;
    float* Cf;
    unsigned short *Ch, *Cl;
    int N, K, nbx;
};

template<bool SPLIT_OUT>
__global__ __launch_bounds__(256, 2) void gemm64(GJob j0, GJob j1, int nblk0)
{
    __shared__ unsigned short Ah_s[64][40];   // +8 pad
    __shared__ unsigned short Al_s[64][40];
    __shared__ unsigned short Wh_s[64][40];
    __shared__ unsigned short Wl_s[64][40];

    const bool first = (int)blockIdx.x < nblk0;
    const GJob J = first ? j0 : j1;
    const int local = first ? (int)blockIdx.x : (int)blockIdx.x - nblk0;
    const int m0 = (local % J.nbx) * 64;
    const int n0 = (local / J.nbx) * 64;

    const int tid  = threadIdx.x;
    const int lane = tid & 63;
    const int wid  = tid >> 6;
    const int wr   = wid >> 1, wc = wid & 1;
    const int row  = tid >> 2, q = (tid & 3) * 8;
    const int lrow = lane & 15, lk = (lane >> 4) * 8;

    const unsigned short* pAh = J.Ah + (size_t)(m0 + row) * J.lda + q;
    const unsigned short* pAl = J.Al + (size_t)(m0 + row) * J.lda + q;
    const unsigned short* pWh = J.Wh + (size_t)(n0 + row) * J.ldw + q;
    const unsigned short* pWl = J.Wl + (size_t)(n0 + row) * J.ldw + q;

    f32x4 acc[2][2];
    #pragma unroll
    for (int i = 0; i < 2; ++i)
        #pragma unroll
        for (int j = 0; j < 2; ++j) acc[i][j] = (f32x4){0.f, 0.f, 0.f, 0.f};

    for (int k0 = 0; k0 < J.K; k0 += 32) {
        u16x8 ra = *(const u16x8*)(pAh + k0);
        u16x8 rb = *(const u16x8*)(pAl + k0);
        u16x8 rc = *(const u16x8*)(pWh + k0);
        u16x8 rd = *(const u16x8*)(pWl + k0);
        if (k0) __syncthreads();
        *(u16x8*)&Ah_s[row][q] = ra;
        *(u16x8*)&Al_s[row][q] = rb;
        *(u16x8*)&Wh_s[row][q] = rc;
        *(u16x8*)&Wl_s[row][q] = rd;
        __syncthreads();

        bf16x8 ah[2], al[2], wh[2], wl[2];
        #pragma unroll
        for (int i = 0; i < 2; ++i) {
            ah[i] = *(const bf16x8*)&Ah_s[wr * 32 + i * 16 + lrow][lk];
            al[i] = *(const bf16x8*)&Al_s[wr * 32 + i * 16 + lrow][lk];
            wh[i] = *(const bf16x8*)&Wh_s[wc * 32 + i * 16 + lrow][lk];
            wl[i] = *(const bf16x8*)&Wl_s[wc * 32 + i * 16 + lrow][lk];
        }
        #pragma unroll
        for (int i = 0; i < 2; ++i)
            #pragma unroll
            for (int j = 0; j < 2; ++j) {
                acc[i][j] = __builtin_amdgcn_mfma_f32_16x16x32_bf16(ah[i], wh[j], acc[i][j], 0, 0, 0);
                acc[i][j] = __builtin_amdgcn_mfma_f32_16x16x32_bf16(ah[i], wl[j], acc[i][j], 0, 0, 0);
                acc[i][j] = __builtin_amdgcn_mfma_f32_16x16x32_bf16(al[i], wh[j], acc[i][j], 0, 0, 0);
            }
    }

    // C/D layout: col = lane&15, row = (lane>>4)*4 + r
    #pragma unroll
    for (int i = 0; i < 2; ++i) {
        const int rbase = m0 + wr * 32 + i * 16 + (lane >> 4) * 4;
        #pragma unroll
        for (int j = 0; j < 2; ++j) {
            const int col = n0 + wc * 32 + j * 16 + (lane & 15);
            const float bv = J.bias ? J.bias[col] : 0.f;
            #pragma unroll
            for (int r = 0; r < 4; ++r) {
                float v = acc[i][j][r] + bv;
                size_t off = (size_t)(rbase + r) * J.N + col;
                if (SPLIT_OUT) {
                    unsigned short h = f2bf(v);
                    J.Ch[off] = h;
                    J.Cl[off] = f2bf(v - bf2f(h));
                } else {
                    J.Cf[off] = v;
                }
            }
        }
    }
}

// ---------------- fused: X = e @ W1^T + b_out  (16 x 256 tile), then
//                  out[(bt),u,v] = X[bt,v] + Y[(b,u),v] streamed (nontemporal)
__global__ __launch_bounds__(256, 2) void fused_x_bcast(
    const unsigned short* __restrict__ eh, const unsigned short* __restrict__ el,
    const unsigned short* __restrict__ W1h, const unsigned short* __restrict__ W1l,
    const float* __restrict__ b_out,
    const float* __restrict__ Y,
    float* __restrict__ out)
{
    __shared__ unsigned short Ah_s[16][40];
    __shared__ unsigned short Al_s[16][40];
    __shared__ unsigned short Wh_s[256][40];
    __shared__ unsigned short Wl_s[256][40];
    __shared__ float Xs[16][260];

    const int tid  = threadIdx.x;
    const int lane = tid & 63;
    const int wid  = tid >> 6;
    const int bt0  = blockIdx.x * 16;
    const int v0   = blockIdx.y * 256;
    const int b    = bt0 >> 8;           // T = 256
    const int lrow = lane & 15, lk = (lane >> 4) * 8;
    const int ldw  = 1024;               // W_out row stride (2J)

    f32x4 acc[4];
    #pragma unroll
    for (int j = 0; j < 4; ++j) acc[j] = (f32x4){0.f, 0.f, 0.f, 0.f};

    for (int k0 = 0; k0 < 512; k0 += 32) {
        u16x8 w_h[4], w_l[4];
        #pragma unroll
        for (int pc = 0; pc < 4; ++pc) {
            const int c = tid + pc * 256;
            const int row = c >> 2, q = (c & 3) * 8;
            w_h[pc] = *(const u16x8*)(W1h + (size_t)(v0 + row) * ldw + k0 + q);
            w_l[pc] = *(const u16x8*)(W1l + (size_t)(v0 + row) * ldw + k0 + q);
        }
        u16x8 a_v = {};
        if (tid < 128) {
            const int c = tid & 63;
            const int row = c >> 2, q = (c & 3) * 8;
            const unsigned short* src = (tid < 64) ? eh : el;
            a_v = *(const u16x8*)(src + (size_t)(bt0 + row) * 512 + k0 + q);
        }
        if (k0) __syncthreads();
        #pragma unroll
        for (int pc = 0; pc < 4; ++pc) {
            const int c = tid + pc * 256;
            const int row = c >> 2, q = (c & 3) * 8;
            *(u16x8*)&Wh_s[row][q] = w_h[pc];
            *(u16x8*)&Wl_s[row][q] = w_l[pc];
        }
        if (tid < 128) {
            const int c = tid & 63;
            const int row = c >> 2, q = (c & 3) * 8;
            if (tid < 64) *(u16x8*)&Ah_s[row][q] = a_v;
            else          *(u16x8*)&Al_s[row][q] = a_v;
        }
        __syncthreads();

        bf16x8 ah = *(const bf16x8*)&Ah_s[lrow][lk];
        bf16x8 al = *(const bf16x8*)&Al_s[lrow][lk];
        #pragma unroll
        for (int j = 0; j < 4; ++j) {
            bf16x8 wh = *(const bf16x8*)&Wh_s[wid * 64 + j * 16 + lrow][lk];
            bf16x8 wl = *(const bf16x8*)&Wl_s[wid * 64 + j * 16 + lrow][lk];
            acc[j] = __builtin_amdgcn_mfma_f32_16x16x32_bf16(ah, wh, acc[j], 0, 0, 0);
            acc[j] = __builtin_amdgcn_mfma_f32_16x16x32_bf16(ah, wl, acc[j], 0, 0, 0);
            acc[j] = __builtin_amdgcn_mfma_f32_16x16x32_bf16(al, wh, acc[j], 0, 0, 0);
        }
    }

    // epilogue: X tile -> LDS (C/D layout: col = lane&15, row = (lane>>4)*4 + r)
    #pragma unroll
    for (int j = 0; j < 4; ++j) {
        const int col = wid * 64 + j * 16 + (lane & 15);
        const float bv = b_out[v0 + col];
        #pragma unroll
        for (int r = 0; r < 4; ++r)
            Xs[(lane >> 4) * 4 + r][col] = acc[j][r] + bv;
    }
    __syncthreads();

    // Y strip -> registers (each thread: 16 u-rows, one f4 column)
    const int vq = tid & 63;     // f4 index within 256-col strip
    const int g  = tid >> 6;     // u mod 4
    const f4* Y4 = (const f4*)Y + (size_t)b * 64 * 256 + v0 / 4 + vq;
    f4 yreg[16];
    #pragma unroll
    for (int uu = 0; uu < 16; ++uu)
        yreg[uu] = Y4[(size_t)(uu * 4 + g) * 256];

    // stream output: out[(bt0+btl)*64 + u][v0 + vq*4 ..]
    f4* O4 = (f4*)out + ((size_t)bt0 * 64 + g) * 256 + v0 / 4 + vq;
    for (int btl = 0; btl < 16; ++btl) {
        f4 xv = *(const f4*)&Xs[btl][vq * 4];
        f4* rowp = O4 + (size_t)btl * 64 * 256;
        #pragma unroll
        for (int uu = 0; uu < 16; ++uu) {
            f4 yv = yreg[uu];
            f4 r = { xv.x + yv.x, xv.y + yv.y, xv.z + yv.z, xv.w + yv.w };
            __builtin_nontemporal_store(r, &rowp[(size_t)uu * 4 * 256]);
        }
    }
}

extern "C" void kernel_launch(void* const* d_in, const int* in_sizes, int n_in,
                              void* d_out, int out_size, void* d_ws, size_t ws_size,
                              hipStream_t stream) {
    (void)in_sizes; (void)n_in; (void)out_size; (void)ws_size;

    const int B = 8, T = 256, U = 64;
    const int ENC = 512, DEC = 640, J = 512, V = 1024;
    const int MT = B * T;   // 2048
    const int MU = B * U;   // 512

    const float* enc    = (const float*)d_in[0];
    const float* pred   = (const float*)d_in[1];
    const float* W_enc  = (const float*)d_in[2];
    const float* b_enc  = (const float*)d_in[3];
    const float* W_pred = (const float*)d_in[4];
    const float* b_pred = (const float*)d_in[5];
    const float* W_out  = (const float*)d_in[6];
    const float* b_out  = (const float*)d_in[7];
    float* out = (float*)d_out;

    const int n_enc  = MT * ENC;
    const int n_pred = MU * DEC;
    const int n_We   = J * ENC;
    const int n_Wp   = J * DEC;
    const int n_Wo   = V * 2 * J;
    const int n_e    = MT * J;
    const int n_p    = MU * J;

    unsigned short* w = (unsigned short*)d_ws;
    unsigned short* enc_h  = w;
    unsigned short* enc_l  = enc_h + n_enc;
    unsigned short* pred_h = enc_l + n_enc;
    unsigned short* pred_l = pred_h + n_pred;
    unsigned short* We_h   = pred_l + n_pred;
    unsigned short* We_l   = We_h + n_We;
    unsigned short* Wp_h   = We_l + n_We;
    unsigned short* Wp_l   = Wp_h + n_Wp;
    unsigned short* Wo_h   = Wp_l + n_Wp;
    unsigned short* Wo_l   = Wo_h + n_Wo;
    unsigned short* e_h    = Wo_l + n_Wo;
    unsigned short* e_l    = e_h + n_e;
    unsigned short* p_h    = e_l + n_e;
    unsigned short* p_l    = p_h + n_p;
    float* ws_Y = (float*)(p_l + n_p);          // (MU, V)

    // 1) convert all f32 inputs to bf16 hi/lo planes
    CvtJob j0 = { enc,    enc_h,  enc_l,  n_enc  / 8 };
    CvtJob j1 = { pred,   pred_h, pred_l, n_pred / 8 };
    CvtJob j2 = { W_enc,  We_h,   We_l,   n_We   / 8 };
    CvtJob j3 = { W_pred, Wp_h,   Wp_l,   n_Wp   / 8 };
    CvtJob j4 = { W_out,  Wo_h,   Wo_l,   n_Wo   / 8 };
    const int total8 = (n_enc + n_pred + n_We + n_Wp + n_Wo) / 8;
    convert_kernel<<<(total8 + 255) / 256, 256, 0, stream>>>(j0, j1, j2, j3, j4, total8);

    // 2) merged e + p GEMMs (split-bf16 planes out)
    GJob je = { enc_h, enc_l, We_h, We_l, ENC, ENC, b_enc,
                nullptr, e_h, e_l, J, ENC, MT / 64 };
    GJob jp = { pred_h, pred_l, Wp_h, Wp_l, DEC, DEC, b_pred,
                nullptr, p_h, p_l, J, DEC, MU / 64 };
    const int nbe = (MT / 64) * (J / 64);   // 256
    const int nbp = (MU / 64) * (J / 64);   // 64
    gemm64<true><<<nbe + nbp, 256, 0, stream>>>(je, jp, nbe);

    // 3) Y = p @ W2^T (f32 out, no bias)
    GJob jy = { p_h, p_l, Wo_h + J, Wo_l + J, J, 2 * J, nullptr,
                ws_Y, nullptr, nullptr, V, J, MU / 64 };
    const int nby = (MU / 64) * (V / 64);   // 128
    gemm64<false><<<nby, 256, 0, stream>>>(jy, jy, nby);

    // 4) fused X-GEMM + broadcast-add + stream out
    fused_x_bcast<<<dim3(MT / 16, V / 256), 256, 0, stream>>>(
        e_h, e_l, Wo_h, Wo_l, b_out, ws_Y, out);
}

// Round 5
// 145.125 us; speedup vs baseline: 1.4293x; 1.4293x over previous
//
#include <hip/hip_runtime.h>

typedef float f4 __attribute__((ext_vector_type(4)));
typedef float f32x4 __attribute__((ext_vector_type(4)));
typedef short bf16x8 __attribute__((ext_vector_type(8)));
typedef unsigned short u16x8 __attribute__((ext_vector_type(8)));

static __device__ __forceinline__ unsigned short f2bf(float f) {
    unsigned int x = __builtin_bit_cast(unsigned int, f);
    x = (x + 0x7fffu + ((x >> 16) & 1u)) >> 16;
    return (unsigned short)x;
}
static __device__ __forceinline__ float bf2f(unsigned short h) {
    unsigned int x = ((unsigned int)h) << 16;
    return __builtin_bit_cast(float, x);
}

// async 16B global->LDS DMA (LDS dest = wave-uniform base + lane*16)
static __device__ __forceinline__ void gll16(const unsigned short* g, unsigned short* l) {
    __builtin_amdgcn_global_load_lds(
        (__attribute__((address_space(1))) void*)(g),
        (__attribute__((address_space(3))) void*)(l), 16, 0, 0);
}

// ---------------- convert: f32 -> (bf16 hi, bf16 lo) planes, 5 tensors fused
struct CvtJob { const float* src; unsigned short* hi; unsigned short* lo; int n8; };

__global__ __launch_bounds__(256) void convert_kernel(
    CvtJob j0, CvtJob j1, CvtJob j2, CvtJob j3, CvtJob j4, int total8)
{
    CvtJob jobs[5] = { j0, j1, j2, j3, j4 };
    int cum1 = j0.n8, cum2 = cum1 + j1.n8, cum3 = cum2 + j2.n8, cum4 = cum3 + j3.n8;
    for (int g = blockIdx.x * blockDim.x + threadIdx.x; g < total8;
         g += gridDim.x * blockDim.x) {
        int ji, base;
        if      (g < cum1) { ji = 0; base = 0; }
        else if (g < cum2) { ji = 1; base = cum1; }
        else if (g < cum3) { ji = 2; base = cum2; }
        else if (g < cum4) { ji = 3; base = cum3; }
        else               { ji = 4; base = cum4; }
        const CvtJob& J = jobs[ji];
        int idx = (g - base) * 8;
        f4 a = *(const f4*)(J.src + idx);
        f4 b = *(const f4*)(J.src + idx + 4);
        u16x8 hv, lv;
        float s[8] = { a.x, a.y, a.z, a.w, b.x, b.y, b.z, b.w };
        #pragma unroll
        for (int i = 0; i < 8; ++i) {
            unsigned short h = f2bf(s[i]);
            hv[i] = h;
            lv[i] = f2bf(s[i] - bf2f(h));
        }
        *(u16x8*)(J.hi + idx) = hv;
        *(u16x8*)(J.lo + idx) = lv;
    }
}

// ---------------- merged split-bf16 MFMA GEMM, 64x64 tiles, async 2-phase
struct GJob {
    const unsigned short *Ah, *Al, *Wh, *Wl;
    int lda, ldw;
    const float* bias;
    float* Cf;
    unsigned short *Ch, *Cl;
    int N, K, nbx;
};

// LDS frag offset (shorts) for row r, true 16B-slot s (source-swizzle inverse)
static __device__ __forceinline__ int fragoff(int r, int s) {
    return r * 32 + ((s ^ ((r >> 1) & 3)) << 3);
}

template<bool SPLIT_OUT>
__global__ __launch_bounds__(256, 3) void gemm64(GJob j0, GJob j1, int nblk0)
{
    // 2 buffers x 4 planes (Ah,Al,Wh,Wl) x [64 rows x 32 k] bf16, linear
    __shared__ unsigned short lds[2][4][64 * 32];

    const bool first = (int)blockIdx.x < nblk0;
    const GJob J = first ? j0 : j1;
    const int local = first ? (int)blockIdx.x : (int)blockIdx.x - nblk0;
    const int m0 = (local % J.nbx) * 64;
    const int n0 = (local / J.nbx) * 64;

    const int tid  = threadIdx.x;
    const int lane = tid & 63;
    const int wid  = tid >> 6;
    const int wr   = wid >> 1, wc = wid & 1;
    const int lrow = lane & 15;
    const int s    = lane >> 4;

    // staging: wave w covers tile rows 16w..16w+15; 4 lanes per row (16B slots).
    // Global source slot is pre-swizzled so linear LDS == swizzled layout.
    const int srow  = wid * 16 + (lane >> 2);
    const int sslot = (lane & 3) ^ ((srow >> 1) & 3);
    const size_t gA = (size_t)(m0 + srow) * J.lda + sslot * 8;
    const size_t gW = (size_t)(n0 + srow) * J.ldw + sslot * 8;

    f32x4 acc[2][2];
    #pragma unroll
    for (int i = 0; i < 2; ++i)
        #pragma unroll
        for (int j = 0; j < 2; ++j) acc[i][j] = (f32x4){0.f, 0.f, 0.f, 0.f};

    const int nt = J.K / 32;

    // prologue: stage tile 0
    gll16(J.Ah + gA, &lds[0][0][wid * 512]);
    gll16(J.Al + gA, &lds[0][1][wid * 512]);
    gll16(J.Wh + gW, &lds[0][2][wid * 512]);
    gll16(J.Wl + gW, &lds[0][3][wid * 512]);
    asm volatile("s_waitcnt vmcnt(0)" ::: "memory");
    __syncthreads();

    int cur = 0;
    for (int t = 0; t < nt; ++t) {
        if (t + 1 < nt) {             // issue next-tile DMA before computing
            const int k0 = (t + 1) * 32;
            gll16(J.Ah + gA + k0, &lds[cur ^ 1][0][wid * 512]);
            gll16(J.Al + gA + k0, &lds[cur ^ 1][1][wid * 512]);
            gll16(J.Wh + gW + k0, &lds[cur ^ 1][2][wid * 512]);
            gll16(J.Wl + gW + k0, &lds[cur ^ 1][3][wid * 512]);
        }

        bf16x8 ah[2], al[2], wh[2], wl[2];
        #pragma unroll
        for (int i = 0; i < 2; ++i) {
            const int ra = wr * 32 + i * 16 + lrow;
            const int rw = wc * 32 + i * 16 + lrow;
            ah[i] = *(const bf16x8*)&lds[cur][0][fragoff(ra, s)];
            al[i] = *(const bf16x8*)&lds[cur][1][fragoff(ra, s)];
            wh[i] = *(const bf16x8*)&lds[cur][2][fragoff(rw, s)];
            wl[i] = *(const bf16x8*)&lds[cur][3][fragoff(rw, s)];
        }
        #pragma unroll
        for (int i = 0; i < 2; ++i)
            #pragma unroll
            for (int j = 0; j < 2; ++j) {
                acc[i][j] = __builtin_amdgcn_mfma_f32_16x16x32_bf16(ah[i], wh[j], acc[i][j], 0, 0, 0);
                acc[i][j] = __builtin_amdgcn_mfma_f32_16x16x32_bf16(ah[i], wl[j], acc[i][j], 0, 0, 0);
                acc[i][j] = __builtin_amdgcn_mfma_f32_16x16x32_bf16(al[i], wh[j], acc[i][j], 0, 0, 0);
            }

        if (t + 1 < nt) {
            asm volatile("s_waitcnt vmcnt(0)" ::: "memory");
            __syncthreads();
            cur ^= 1;
        }
    }

    // epilogue: C/D layout col = lane&15, row = (lane>>4)*4 + r
    #pragma unroll
    for (int i = 0; i < 2; ++i) {
        const int rbase = m0 + wr * 32 + i * 16 + (lane >> 4) * 4;
        #pragma unroll
        for (int j = 0; j < 2; ++j) {
            const int col = n0 + wc * 32 + j * 16 + (lane & 15);
            const float bv = J.bias ? J.bias[col] : 0.f;
            #pragma unroll
            for (int r = 0; r < 4; ++r) {
                float v = acc[i][j][r] + bv;
                size_t off = (size_t)(rbase + r) * J.N + col;
                if (SPLIT_OUT) {
                    unsigned short h = f2bf(v);
                    J.Ch[off] = h;
                    J.Cl[off] = f2bf(v - bf2f(h));
                } else {
                    J.Cf[off] = v;
                }
            }
        }
    }
}

// ---------------- broadcast add: out[(b,t),u,:] = X[(b,t),:] + Y[(b,u),:]
__global__ __launch_bounds__(256) void bcast_kernel(
    const float* __restrict__ X, const float* __restrict__ Y,
    float* __restrict__ out, int T, int U)
{
    const int Vq  = 256;           // 1024 / 4
    const int bt  = blockIdx.x;
    const int b   = bt / T;
    const int tid = threadIdx.x;

    const f4* X4 = (const f4*)X;
    const f4* Y4 = (const f4*)Y + (size_t)b * U * Vq;
    f4* O4 = (f4*)out + (size_t)bt * U * Vq;

    f4 x = X4[(size_t)bt * Vq + tid];
    #pragma unroll 4
    for (int u = 0; u < U; ++u) {
        f4 y = Y4[u * Vq + tid];
        f4 r = { x.x + y.x, x.y + y.y, x.z + y.z, x.w + y.w };
        __builtin_nontemporal_store(r, &O4[u * Vq + tid]);
    }
}

extern "C" void kernel_launch(void* const* d_in, const int* in_sizes, int n_in,
                              void* d_out, int out_size, void* d_ws, size_t ws_size,
                              hipStream_t stream) {
    (void)in_sizes; (void)n_in; (void)out_size; (void)ws_size;

    const int B = 8, T = 256, U = 64;
    const int ENC = 512, DEC = 640, J = 512, V = 1024;
    const int MT = B * T;   // 2048
    const int MU = B * U;   // 512

    const float* enc    = (const float*)d_in[0];
    const float* pred   = (const float*)d_in[1];
    const float* W_enc  = (const float*)d_in[2];
    const float* b_enc  = (const float*)d_in[3];
    const float* W_pred = (const float*)d_in[4];
    const float* b_pred = (const float*)d_in[5];
    const float* W_out  = (const float*)d_in[6];
    const float* b_out  = (const float*)d_in[7];
    float* out = (float*)d_out;

    const int n_enc  = MT * ENC;
    const int n_pred = MU * DEC;
    const int n_We   = J * ENC;
    const int n_Wp   = J * DEC;
    const int n_Wo   = V * 2 * J;
    const int n_e    = MT * J;
    const int n_p    = MU * J;

    unsigned short* w = (unsigned short*)d_ws;
    unsigned short* enc_h  = w;
    unsigned short* enc_l  = enc_h + n_enc;
    unsigned short* pred_h = enc_l + n_enc;
    unsigned short* pred_l = pred_h + n_pred;
    unsigned short* We_h   = pred_l + n_pred;
    unsigned short* We_l   = We_h + n_We;
    unsigned short* Wp_h   = We_l + n_We;
    unsigned short* Wp_l   = Wp_h + n_Wp;
    unsigned short* Wo_h   = Wp_l + n_Wp;
    unsigned short* Wo_l   = Wo_h + n_Wo;
    unsigned short* e_h    = Wo_l + n_Wo;
    unsigned short* e_l    = e_h + n_e;
    unsigned short* p_h    = e_l + n_e;
    unsigned short* p_l    = p_h + n_p;
    float* ws_X = (float*)(p_l + n_p);          // (MT, V)
    float* ws_Y = ws_X + (size_t)MT * V;        // (MU, V)

    // 1) convert all f32 inputs to bf16 hi/lo planes
    CvtJob j0 = { enc,    enc_h,  enc_l,  n_enc  / 8 };
    CvtJob j1 = { pred,   pred_h, pred_l, n_pred / 8 };
    CvtJob j2 = { W_enc,  We_h,   We_l,   n_We   / 8 };
    CvtJob j3 = { W_pred, Wp_h,   Wp_l,   n_Wp   / 8 };
    CvtJob j4 = { W_out,  Wo_h,   Wo_l,   n_Wo   / 8 };
    const int total8 = (n_enc + n_pred + n_We + n_Wp + n_Wo) / 8;
    convert_kernel<<<(total8 + 255) / 256, 256, 0, stream>>>(j0, j1, j2, j3, j4, total8);

    // 2) merged e + p GEMMs (split-bf16 planes out)
    GJob je = { enc_h, enc_l, We_h, We_l, ENC, ENC, b_enc,
                nullptr, e_h, e_l, J, ENC, MT / 64 };
    GJob jp = { pred_h, pred_l, Wp_h, Wp_l, DEC, DEC, b_pred,
                nullptr, p_h, p_l, J, DEC, MU / 64 };
    const int nbe = (MT / 64) * (J / 64);   // 256
    const int nbp = (MU / 64) * (J / 64);   // 64
    gemm64<true><<<nbe + nbp, 256, 0, stream>>>(je, jp, nbe);

    // 3) merged X + Y GEMMs (f32 out)
    GJob jx = { e_h, e_l, Wo_h, Wo_l, J, 2 * J, b_out,
                ws_X, nullptr, nullptr, V, J, MT / 64 };
    GJob jy = { p_h, p_l, Wo_h + J, Wo_l + J, J, 2 * J, nullptr,
                ws_Y, nullptr, nullptr, V, J, MU / 64 };
    const int nbx = (MT / 64) * (V / 64);   // 512
    const int nby = (MU / 64) * (V / 64);   // 128
    gemm64<false><<<nbx + nby, 256, 0, stream>>>(jx, jy, nbx);

    // 4) out = X broadcast + Y
    bcast_kernel<<<dim3(B * T), 256, 0, stream>>>(ws_X, ws_Y, out, T, U);
}